// Round 1
// baseline (3264.975 us; speedup 1.0000x reference)
//
#include <hip/hip_runtime.h>
#include <hip/hip_bf16.h>
#include <type_traits>

#define DEV __device__ __forceinline__

using bf16 = __hip_bfloat16;

constexpr int Bq = 16, Tq = 1024, Eq = 1024, Gq = 4, Nq = 8, Dq = 128, Vq = 2048;
constexpr int M1 = Bq * Tq;       // 16384 rows (b,t)
constexpr int N1 = Gq * Nq * Dq;  // 4096
constexpr int K1 = Eq;            // 1024
constexpr int K2 = Nq * Dq;       // 1024
constexpr int N2 = Vq;            // 2048

DEV float toF(float x) { return x; }
DEV float toF(bf16 x) { return __bfloat162float(x); }

DEV unsigned int bfbits(float x) {
  bf16 h = __float2bfloat16(x);
  union { bf16 h; unsigned short u; } cv;
  cv.h = h;
  return (unsigned int)cv.u;
}

template <typename T> DEV T fromF(float x);
template <> DEV float fromF<float>(float x) { return x; }
template <> DEV bf16 fromF<bf16>(float x) { return __float2bfloat16(x); }

DEV float sigm(float x) { return 1.0f / (1.0f + __expf(-x)); }
DEV float tanh_(float x) { return 2.0f / (1.0f + __expf(-2.0f * x)) - 1.0f; }

// ---------------------------------------------------------------------------
// Kernel 1: Wx = x_emb[M1,K1] @ W_in[K1,N1]  (f32 tiled GEMM, 128x128 tile)
// ---------------------------------------------------------------------------
template <typename TW>
__global__ __launch_bounds__(256) void gemm_xw(const float* __restrict__ A,
                                               const float* __restrict__ Bm,
                                               TW* __restrict__ C) {
  __shared__ float As[16][132];
  __shared__ float Bs[16][132];
  const int m0 = blockIdx.y * 128, n0 = blockIdx.x * 128;
  const int tid = threadIdx.x;
  const int ty = tid >> 4, tx = tid & 15;
  float acc[8][8];
#pragma unroll
  for (int i = 0; i < 8; ++i)
#pragma unroll
    for (int j = 0; j < 8; ++j) acc[i][j] = 0.f;

  for (int k0 = 0; k0 < K1; k0 += 16) {
    {
      const int r = tid >> 1, kk = (tid & 1) * 8;
      const float* src = A + (size_t)(m0 + r) * K1 + k0 + kk;
      float4 v0 = *(const float4*)src;
      float4 v1 = *(const float4*)(src + 4);
      As[kk + 0][r] = v0.x; As[kk + 1][r] = v0.y;
      As[kk + 2][r] = v0.z; As[kk + 3][r] = v0.w;
      As[kk + 4][r] = v1.x; As[kk + 5][r] = v1.y;
      As[kk + 6][r] = v1.z; As[kk + 7][r] = v1.w;
    }
    {
      const int kr = tid >> 4, nn = (tid & 15) * 8;
      const float* src = Bm + (size_t)(k0 + kr) * N1 + n0 + nn;
      *(float4*)&Bs[kr][nn] = *(const float4*)src;
      *(float4*)&Bs[kr][nn + 4] = *(const float4*)(src + 4);
    }
    __syncthreads();
#pragma unroll
    for (int k = 0; k < 16; ++k) {
      float a[8], b[8];
      *(float4*)&a[0] = *(const float4*)&As[k][ty * 8];
      *(float4*)&a[4] = *(const float4*)&As[k][ty * 8 + 4];
      *(float4*)&b[0] = *(const float4*)&Bs[k][tx * 8];
      *(float4*)&b[4] = *(const float4*)&Bs[k][tx * 8 + 4];
#pragma unroll
      for (int i = 0; i < 8; ++i)
#pragma unroll
        for (int j = 0; j < 8; ++j) acc[i][j] += a[i] * b[j];
    }
    __syncthreads();
  }
#pragma unroll
  for (int i = 0; i < 8; ++i) {
    const size_t row = (size_t)(m0 + ty * 8 + i);
    TW* dst = C + row * (size_t)N1 + n0 + tx * 8;
    if constexpr (std::is_same_v<TW, float>) {
      *(float4*)dst = make_float4(acc[i][0], acc[i][1], acc[i][2], acc[i][3]);
      *(float4*)(dst + 4) = make_float4(acc[i][4], acc[i][5], acc[i][6], acc[i][7]);
    } else {
      uint4 u;
      u.x = bfbits(acc[i][0]) | (bfbits(acc[i][1]) << 16);
      u.y = bfbits(acc[i][2]) | (bfbits(acc[i][3]) << 16);
      u.z = bfbits(acc[i][4]) | (bfbits(acc[i][5]) << 16);
      u.w = bfbits(acc[i][6]) | (bfbits(acc[i][7]) << 16);
      *(uint4*)dst = u;
    }
  }
}

// ---------------------------------------------------------------------------
// Kernel 2: LSTM recurrence. One WG per (b,n) chain -> 128 WGs, 512 threads.
// Thread t owns gate row (g = t>>7, d = t&127): R[g,n,d,:] lives in VGPRs.
// ---------------------------------------------------------------------------
template <typename TW, typename TH>
__global__ __launch_bounds__(512) void lstm_rec(const TW* __restrict__ Wx,
                                                const float* __restrict__ R,
                                                const float* __restrict__ bias,
                                                TH* __restrict__ h_all) {
  const int wg = blockIdx.x;
  const int bb = wg >> 3;  // batch
  const int n = wg & 7;    // head
  const int t = threadIdx.x;
  const int g = t >> 7, d = t & 127;

  float rrow[128];
  const float* Rr = R + (size_t)((g * Nq + n) * Dq + d) * Dq;
#pragma unroll
  for (int e4 = 0; e4 < 32; ++e4) {
    float4 v = *(const float4*)(Rr + e4 * 4);
    rrow[4 * e4 + 0] = v.x; rrow[4 * e4 + 1] = v.y;
    rrow[4 * e4 + 2] = v.z; rrow[4 * e4 + 3] = v.w;
  }
  const float bv = bias[(g * Nq + n) * Dq + d];

  __shared__ __align__(16) float h_lds[128];
  __shared__ float gl[4][128];
  float c = 0.f;
  if (t < 128) h_lds[t] = 0.f;
  __syncthreads();

  const TW* wxp = Wx + ((size_t)(bb * Tq) * Gq + g) * (size_t)(Nq * Dq) + n * Dq + d;
  float wx_next = toF(*wxp);

  for (int step = 0; step < Tq; ++step) {
    const float wx = wx_next;
    if (step < Tq - 1) wx_next = toF(wxp[(size_t)(step + 1) * N1]);

    float a0 = 0.f, a1 = 0.f, a2 = 0.f, a3 = 0.f;
    const float4* h4 = (const float4*)h_lds;
#pragma unroll
    for (int e = 0; e < 32; ++e) {
      float4 hv = h4[e];
      a0 += rrow[4 * e + 0] * hv.x;
      a1 += rrow[4 * e + 1] * hv.y;
      a2 += rrow[4 * e + 2] * hv.z;
      a3 += rrow[4 * e + 3] * hv.w;
    }
    const float pre = wx + bv + ((a0 + a1) + (a2 + a3));
    const float gv = (g == 2) ? tanh_(pre) : sigm(pre);
    gl[g][d] = gv;
    __syncthreads();
    if (t < 128) {
      const float iv = gl[0][t], fv = gl[1][t], zv = gl[2][t], ov = gl[3][t];
      c = fv * c + iv * zv;
      const float h = ov * tanh_(c);
      h_lds[t] = h;
      h_all[((size_t)(bb * Tq + step) * Nq + n) * Dq + t] = fromF<TH>(h);
    }
    __syncthreads();
  }
}

// ---------------------------------------------------------------------------
// Kernel 3: logits = h_all[M1,K2] @ W_proj[N2,K2]^T + b_proj
// ---------------------------------------------------------------------------
template <typename TH>
__global__ __launch_bounds__(256) void gemm_out(const TH* __restrict__ A,
                                                const float* __restrict__ Wp,
                                                const float* __restrict__ bp,
                                                float* __restrict__ C) {
  __shared__ float As[16][132];
  __shared__ float Bs[16][132];
  const int m0 = blockIdx.y * 128, n0 = blockIdx.x * 128;
  const int tid = threadIdx.x;
  const int ty = tid >> 4, tx = tid & 15;
  float acc[8][8];
#pragma unroll
  for (int i = 0; i < 8; ++i)
#pragma unroll
    for (int j = 0; j < 8; ++j) acc[i][j] = 0.f;

  for (int k0 = 0; k0 < K2; k0 += 16) {
    {
      const int r = tid >> 1, kk = (tid & 1) * 8;
      const TH* src = A + (size_t)(m0 + r) * K2 + k0 + kk;
      if constexpr (std::is_same_v<TH, float>) {
        float4 v0 = *(const float4*)src;
        float4 v1 = *(const float4*)(src + 4);
        As[kk + 0][r] = v0.x; As[kk + 1][r] = v0.y;
        As[kk + 2][r] = v0.z; As[kk + 3][r] = v0.w;
        As[kk + 4][r] = v1.x; As[kk + 5][r] = v1.y;
        As[kk + 6][r] = v1.z; As[kk + 7][r] = v1.w;
      } else {
        uint4 u = *(const uint4*)src;
        As[kk + 0][r] = __uint_as_float(u.x << 16);
        As[kk + 1][r] = __uint_as_float(u.x & 0xffff0000u);
        As[kk + 2][r] = __uint_as_float(u.y << 16);
        As[kk + 3][r] = __uint_as_float(u.y & 0xffff0000u);
        As[kk + 4][r] = __uint_as_float(u.z << 16);
        As[kk + 5][r] = __uint_as_float(u.z & 0xffff0000u);
        As[kk + 6][r] = __uint_as_float(u.w << 16);
        As[kk + 7][r] = __uint_as_float(u.w & 0xffff0000u);
      }
    }
    {
      // W_proj is [V, K2] row-major; we need Bs[k][v] (transpose-load)
      const int v = tid >> 1, kk = (tid & 1) * 8;
      const float* src = Wp + (size_t)(n0 + v) * K2 + k0 + kk;
      float4 v0 = *(const float4*)src;
      float4 v1 = *(const float4*)(src + 4);
      Bs[kk + 0][v] = v0.x; Bs[kk + 1][v] = v0.y;
      Bs[kk + 2][v] = v0.z; Bs[kk + 3][v] = v0.w;
      Bs[kk + 4][v] = v1.x; Bs[kk + 5][v] = v1.y;
      Bs[kk + 6][v] = v1.z; Bs[kk + 7][v] = v1.w;
    }
    __syncthreads();
#pragma unroll
    for (int k = 0; k < 16; ++k) {
      float a[8], b[8];
      *(float4*)&a[0] = *(const float4*)&As[k][ty * 8];
      *(float4*)&a[4] = *(const float4*)&As[k][ty * 8 + 4];
      *(float4*)&b[0] = *(const float4*)&Bs[k][tx * 8];
      *(float4*)&b[4] = *(const float4*)&Bs[k][tx * 8 + 4];
#pragma unroll
      for (int i = 0; i < 8; ++i)
#pragma unroll
        for (int j = 0; j < 8; ++j) acc[i][j] += a[i] * b[j];
    }
    __syncthreads();
  }
  float bias8[8];
#pragma unroll
  for (int j = 0; j < 8; ++j) bias8[j] = bp[n0 + tx * 8 + j];
#pragma unroll
  for (int i = 0; i < 8; ++i) {
    const size_t row = (size_t)(m0 + ty * 8 + i);
    float* dst = C + row * (size_t)N2 + n0 + tx * 8;
    *(float4*)dst = make_float4(acc[i][0] + bias8[0], acc[i][1] + bias8[1],
                                acc[i][2] + bias8[2], acc[i][3] + bias8[3]);
    *(float4*)(dst + 4) = make_float4(acc[i][4] + bias8[4], acc[i][5] + bias8[5],
                                      acc[i][6] + bias8[6], acc[i][7] + bias8[7]);
  }
}

// ---------------------------------------------------------------------------
extern "C" void kernel_launch(void* const* d_in, const int* in_sizes, int n_in,
                              void* d_out, int out_size, void* d_ws, size_t ws_size,
                              hipStream_t stream) {
  const float* x_emb = (const float*)d_in[0];   // [16,1024,1024]
  const float* W_in  = (const float*)d_in[1];   // [1024,4096]
  const float* R     = (const float*)d_in[2];   // [4,8,128,128]
  const float* bias  = (const float*)d_in[3];   // [4,8,128]
  const float* W_prj = (const float*)d_in[4];   // [2048,1024]
  const float* b_prj = (const float*)d_in[5];   // [2048]
  float* out = (float*)d_out;                   // [16,1024,2048] f32

  const size_t wxF = (size_t)M1 * N1 * sizeof(float);   // 256 MB
  const size_t hF  = (size_t)M1 * K2 * sizeof(float);   // 64 MB
  char* ws = (char*)d_ws;

  const dim3 g1(N1 / 128, M1 / 128), b256(256);
  const dim3 gr(Bq * Nq), b512(512);
  const dim3 g2(N2 / 128, M1 / 128);

  if (ws_size >= wxF + hF) {
    float* Wx = (float*)ws;
    float* H  = (float*)(ws + wxF);
    gemm_xw<float><<<g1, b256, 0, stream>>>(x_emb, W_in, Wx);
    lstm_rec<float, float><<<gr, b512, 0, stream>>>(Wx, R, bias, H);
    gemm_out<float><<<g2, b256, 0, stream>>>(H, W_prj, b_prj, out);
  } else if (ws_size >= wxF / 2 + hF) {
    bf16* Wx = (bf16*)ws;
    float* H = (float*)(ws + wxF / 2);
    gemm_xw<bf16><<<g1, b256, 0, stream>>>(x_emb, W_in, Wx);
    lstm_rec<bf16, float><<<gr, b512, 0, stream>>>(Wx, R, bias, H);
    gemm_out<float><<<g2, b256, 0, stream>>>(H, W_prj, b_prj, out);
  } else {
    bf16* Wx = (bf16*)ws;
    bf16* H  = (bf16*)(ws + wxF / 2);
    gemm_xw<bf16><<<g1, b256, 0, stream>>>(x_emb, W_in, Wx);
    lstm_rec<bf16, bf16><<<gr, b512, 0, stream>>>(Wx, R, bias, H);
    gemm_out<bf16><<<g2, b256, 0, stream>>>(H, W_prj, b_prj, out);
  }
}

// Round 2
// 1219.269 us; speedup vs baseline: 2.6778x; 2.6778x over previous
//
#include <hip/hip_runtime.h>
#include <hip/hip_bf16.h>

#define DEV __device__ __forceinline__

using bf16 = __hip_bfloat16;
typedef __attribute__((ext_vector_type(8))) short short8v;  // 8 bf16 = 4 VGPRs
typedef __attribute__((ext_vector_type(4))) float f32x4;

constexpr int Bq = 16, Tq = 1024, Eq = 1024, Gq = 4, Nq = 8, Dq = 128, Vq = 2048;
constexpr int M1 = Bq * Tq;        // 16384
constexpr int N1q = Gq * Nq * Dq;  // 4096
constexpr int K1 = Eq;             // 1024
constexpr int K2 = Nq * Dq;        // 1024
constexpr int N2 = Vq;             // 2048

DEV float toF(float x) { return x; }
DEV float toF(bf16 x) { return __bfloat162float(x); }

template <typename T> DEV T fromF(float x);
template <> DEV float fromF<float>(float x) { return x; }
template <> DEV bf16 fromF<bf16>(float x) { return __float2bfloat16(x); }

DEV unsigned short bfu(float x) {
  union { bf16 h; unsigned short u; } cv;
  cv.h = __float2bfloat16(x);
  return cv.u;
}

DEV float sigm(float x) { return 1.0f / (1.0f + __expf(-x)); }
DEV float tanh_(float x) { return 2.0f / (1.0f + __expf(-2.0f * x)) - 1.0f; }

// async global->LDS, 16B per lane; LDS dest is wave-uniform base + lane*16
#define GLD16(gp, lp)                                                       \
  __builtin_amdgcn_global_load_lds(                                        \
      (const __attribute__((address_space(1))) void*)(gp),                 \
      (__attribute__((address_space(3))) void*)(lp), 16, 0, 0)

// ---------------------------------------------------------------------------
// Prep kernels: casts + transpose-cast
// ---------------------------------------------------------------------------
__global__ __launch_bounds__(256) void cast_f32_bf16(const float* __restrict__ s,
                                                     bf16* __restrict__ d, int n4) {
  const int i = blockIdx.x * 256 + threadIdx.x;
  if (i >= n4) return;
  const float4 v = ((const float4*)s)[i];
  ushort4 u;
  u.x = bfu(v.x); u.y = bfu(v.y); u.z = bfu(v.z); u.w = bfu(v.w);
  ((ushort4*)d)[i] = u;
}

// s: [SK][SN] f32 row-major  ->  d: [SN][SK] bf16 row-major
__global__ __launch_bounds__(256) void transpose_cast(const float* __restrict__ s,
                                                      bf16* __restrict__ d,
                                                      int SK, int SN) {
  __shared__ float t[32][33];
  const int n0 = blockIdx.x * 32, k0 = blockIdx.y * 32;
  const int tx = threadIdx.x & 31, ty = threadIdx.x >> 5;  // ty: 0..7
#pragma unroll
  for (int i = 0; i < 32; i += 8)
    t[ty + i][tx] = s[(size_t)(k0 + ty + i) * SN + n0 + tx];
  __syncthreads();
#pragma unroll
  for (int i = 0; i < 32; i += 8)
    d[(size_t)(n0 + ty + i) * SK + k0 + tx] = __float2bfloat16(t[tx][ty + i]);
}

// ---------------------------------------------------------------------------
// bf16 MFMA GEMM, m97 structure: C[M,N] = A[M,K] @ Bt[N,K]^T
// 128x128 tile, 4 waves (2x2), 4x4 fragments of 16x16x32, BK=32,
// global_load_lds(16B) staging, 2 barriers per K-step.
// ---------------------------------------------------------------------------
template <bool BF16_OUT, bool ADD_BIAS>
__global__ __launch_bounds__(256) void gemm_bt(const bf16* __restrict__ A,
                                               const bf16* __restrict__ Bt,
                                               void* __restrict__ Cout,
                                               const float* __restrict__ bp,
                                               int K, int N) {
  __shared__ bf16 As[128 * 32];
  __shared__ bf16 Bs[128 * 32];
  const int m0 = blockIdx.y * 128, n0 = blockIdx.x * 128;
  const int tid = threadIdx.x;
  const int lane = tid & 63, w = tid >> 6;
  const int wm = w >> 1, wn = w & 1;

  // staging: each wave stages chunks {2w, 2w+1} of A and B (16 rows x 32 cols each)
  const int srow = lane >> 2, scol = (lane & 3) * 8;
  const int ca = w * 2;
  const bf16* Ag0 = A + (size_t)(m0 + ca * 16 + srow) * K + scol;
  const bf16* Ag1 = Ag0 + (size_t)16 * K;
  const bf16* Bg0 = Bt + (size_t)(n0 + ca * 16 + srow) * K + scol;
  const bf16* Bg1 = Bg0 + (size_t)16 * K;
  bf16* Al0 = As + ca * 512;
  bf16* Al1 = Al0 + 512;
  bf16* Bl0 = Bs + ca * 512;
  bf16* Bl1 = Bl0 + 512;

  f32x4 acc[4][4] = {};

  const int rr = lane & 15;           // row within fragment
  const int kb = (lane >> 4) * 8;     // k-slice within fragment

  for (int k0 = 0; k0 < K; k0 += 32) {
    GLD16(Ag0 + k0, Al0);
    GLD16(Ag1 + k0, Al1);
    GLD16(Bg0 + k0, Bl0);
    GLD16(Bg1 + k0, Bl1);
    __syncthreads();
    short8v af[4], bfr[4];
#pragma unroll
    for (int i = 0; i < 4; ++i) {
      af[i]  = *(const short8v*)&As[(wm * 64 + i * 16 + rr) * 32 + kb];
      bfr[i] = *(const short8v*)&Bs[(wn * 64 + i * 16 + rr) * 32 + kb];
    }
#pragma unroll
    for (int i = 0; i < 4; ++i)
#pragma unroll
      for (int j = 0; j < 4; ++j)
        acc[i][j] = __builtin_amdgcn_mfma_f32_16x16x32_bf16(af[i], bfr[j], acc[i][j], 0, 0, 0);
    __syncthreads();
  }

  // epilogue: C/D layout col=lane&15, row=(lane>>4)*4+reg
  const int crow = (lane >> 4) * 4, ccol = lane & 15;
  if constexpr (BF16_OUT) {
    bf16* C = (bf16*)Cout;
#pragma unroll
    for (int i = 0; i < 4; ++i)
#pragma unroll
      for (int j = 0; j < 4; ++j) {
        const size_t base =
            (size_t)(m0 + wm * 64 + i * 16 + crow) * N + (n0 + wn * 64 + j * 16 + ccol);
#pragma unroll
        for (int jj = 0; jj < 4; ++jj)
          C[base + (size_t)jj * N] = __float2bfloat16(acc[i][j][jj]);
      }
  } else {
    float* C = (float*)Cout;
    float bv[4];
#pragma unroll
    for (int j = 0; j < 4; ++j)
      bv[j] = ADD_BIAS ? bp[n0 + wn * 64 + j * 16 + ccol] : 0.f;
#pragma unroll
    for (int i = 0; i < 4; ++i)
#pragma unroll
      for (int j = 0; j < 4; ++j) {
        const size_t base =
            (size_t)(m0 + wm * 64 + i * 16 + crow) * N + (n0 + wn * 64 + j * 16 + ccol);
#pragma unroll
        for (int jj = 0; jj < 4; ++jj)
          C[base + (size_t)jj * N] = acc[i][j][jj] + bv[j];
      }
  }
}

// ---------------------------------------------------------------------------
// LSTM recurrence (unchanged from round 1). One WG per (b,n) chain.
// ---------------------------------------------------------------------------
template <typename TW, typename TH>
__global__ __launch_bounds__(512) void lstm_rec(const TW* __restrict__ Wx,
                                                const float* __restrict__ R,
                                                const float* __restrict__ bias,
                                                TH* __restrict__ h_all) {
  const int wg = blockIdx.x;
  const int bb = wg >> 3;
  const int n = wg & 7;
  const int t = threadIdx.x;
  const int g = t >> 7, d = t & 127;

  float rrow[128];
  const float* Rr = R + (size_t)((g * Nq + n) * Dq + d) * Dq;
#pragma unroll
  for (int e4 = 0; e4 < 32; ++e4) {
    float4 v = *(const float4*)(Rr + e4 * 4);
    rrow[4 * e4 + 0] = v.x; rrow[4 * e4 + 1] = v.y;
    rrow[4 * e4 + 2] = v.z; rrow[4 * e4 + 3] = v.w;
  }
  const float bv = bias[(g * Nq + n) * Dq + d];

  __shared__ __align__(16) float h_lds[128];
  __shared__ float gl[4][128];
  float c = 0.f;
  if (t < 128) h_lds[t] = 0.f;
  __syncthreads();

  const TW* wxp = Wx + ((size_t)(bb * Tq) * Gq + g) * (size_t)(Nq * Dq) + n * Dq + d;
  float wx_next = toF(*wxp);

  for (int step = 0; step < Tq; ++step) {
    const float wx = wx_next;
    if (step < Tq - 1) wx_next = toF(wxp[(size_t)(step + 1) * N1q]);

    float a0 = 0.f, a1 = 0.f, a2 = 0.f, a3 = 0.f;
    const float4* h4 = (const float4*)h_lds;
#pragma unroll
    for (int e = 0; e < 32; ++e) {
      float4 hv = h4[e];
      a0 += rrow[4 * e + 0] * hv.x;
      a1 += rrow[4 * e + 1] * hv.y;
      a2 += rrow[4 * e + 2] * hv.z;
      a3 += rrow[4 * e + 3] * hv.w;
    }
    const float pre = wx + bv + ((a0 + a1) + (a2 + a3));
    const float gv = (g == 2) ? tanh_(pre) : sigm(pre);
    gl[g][d] = gv;
    __syncthreads();
    if (t < 128) {
      const float iv = gl[0][t], fv = gl[1][t], zv = gl[2][t], ov = gl[3][t];
      c = fv * c + iv * zv;
      const float h = ov * tanh_(c);
      h_lds[t] = h;
      h_all[((size_t)(bb * Tq + step) * Nq + n) * Dq + t] = fromF<TH>(h);
    }
    __syncthreads();
  }
}

// ---------------------------------------------------------------------------
extern "C" void kernel_launch(void* const* d_in, const int* in_sizes, int n_in,
                              void* d_out, int out_size, void* d_ws, size_t ws_size,
                              hipStream_t stream) {
  const float* x_emb = (const float*)d_in[0];  // [16,1024,1024]
  const float* W_in  = (const float*)d_in[1];  // [1024,4096]
  const float* R     = (const float*)d_in[2];  // [4,8,128,128]
  const float* bias  = (const float*)d_in[3];  // [4,8,128]
  const float* W_prj = (const float*)d_in[4];  // [2048,1024]
  const float* b_prj = (const float*)d_in[5];  // [2048]

  char* ws = (char*)d_ws;
  bf16* xb  = (bf16*)ws;                               // 32 MB: x_emb bf16 [16384,1024]
  bf16* WiT = (bf16*)(ws + (size_t)M1 * K1 * 2);       //  8 MB: W_in^T bf16 [4096,1024]
  bf16* Wpb = WiT + (size_t)N1q * K1;                  //  4 MB: W_proj bf16 [2048,1024]
  bf16* H   = Wpb + (size_t)N2 * K2;                   // 32 MB: h bf16 [16384,1024]
  // Wx (bf16, [16384,4096] = 134 MB) lives in d_out; it is fully dead before
  // gemm_out overwrites d_out with the f32 logits.
  bf16* Wx = (bf16*)d_out;

  cast_f32_bf16<<<(M1 * K1 / 4 + 255) / 256, 256, 0, stream>>>(x_emb, xb, M1 * K1 / 4);
  transpose_cast<<<dim3(N1q / 32, K1 / 32), 256, 0, stream>>>(W_in, WiT, K1, N1q);
  cast_f32_bf16<<<(N2 * K2 / 4 + 255) / 256, 256, 0, stream>>>(W_prj, Wpb, N2 * K2 / 4);

  gemm_bt<true, false><<<dim3(N1q / 128, M1 / 128), 256, 0, stream>>>(
      xb, WiT, (void*)Wx, nullptr, K1, N1q);

  lstm_rec<bf16, bf16><<<dim3(Bq * Nq), 512, 0, stream>>>(Wx, R, bias, H);

  gemm_bt<false, true><<<dim3(N2 / 128, M1 / 128), 256, 0, stream>>>(
      H, Wpb, d_out, b_prj, K2, N2);
}

// Round 3
// 1098.485 us; speedup vs baseline: 2.9723x; 1.1100x over previous
//
#include <hip/hip_runtime.h>
#include <hip/hip_bf16.h>

#define DEV __device__ __forceinline__

using bf16 = __hip_bfloat16;
typedef __attribute__((ext_vector_type(8))) short short8v;  // 8 bf16 = 4 VGPRs
typedef __attribute__((ext_vector_type(4))) float f32x4;

constexpr int Bq = 16, Tq = 1024, Eq = 1024, Gq = 4, Nq = 8, Dq = 128, Vq = 2048;
constexpr int M1 = Bq * Tq;        // 16384
constexpr int N1q = Gq * Nq * Dq;  // 4096
constexpr int K1 = Eq;             // 1024
constexpr int K2 = Nq * Dq;        // 1024
constexpr int N2 = Vq;             // 2048

DEV unsigned short bfu(float x) {
  union { bf16 h; unsigned short u; } cv;
  cv.h = __float2bfloat16(x);
  return cv.u;
}

DEV float sigm(float x) { return 1.0f / (1.0f + __expf(-x)); }
DEV float tanh_(float x) { return 2.0f / (1.0f + __expf(-2.0f * x)) - 1.0f; }

// async global->LDS, 16B per lane; LDS dest is wave-uniform base + lane*16
#define GLD16(gp, lp)                                                       \
  __builtin_amdgcn_global_load_lds(                                        \
      (const __attribute__((address_space(1))) void*)(gp),                 \
      (__attribute__((address_space(3))) void*)(lp), 16, 0, 0)

// ---------------------------------------------------------------------------
// Prep kernels: casts + transpose-cast
// ---------------------------------------------------------------------------
__global__ __launch_bounds__(256) void cast_f32_bf16(const float* __restrict__ s,
                                                     bf16* __restrict__ d, int n4) {
  const int i = blockIdx.x * 256 + threadIdx.x;
  if (i >= n4) return;
  const float4 v = ((const float4*)s)[i];
  ushort4 u;
  u.x = bfu(v.x); u.y = bfu(v.y); u.z = bfu(v.z); u.w = bfu(v.w);
  ((ushort4*)d)[i] = u;
}

// s: [SK][SN] f32 row-major  ->  d: [SN][SK] bf16 row-major
__global__ __launch_bounds__(256) void transpose_cast(const float* __restrict__ s,
                                                      bf16* __restrict__ d,
                                                      int SK, int SN) {
  __shared__ float t[32][33];
  const int n0 = blockIdx.x * 32, k0 = blockIdx.y * 32;
  const int tx = threadIdx.x & 31, ty = threadIdx.x >> 5;  // ty: 0..7
#pragma unroll
  for (int i = 0; i < 32; i += 8)
    t[ty + i][tx] = s[(size_t)(k0 + ty + i) * SN + n0 + tx];
  __syncthreads();
#pragma unroll
  for (int i = 0; i < 32; i += 8)
    d[(size_t)(n0 + ty + i) * SK + k0 + tx] = __float2bfloat16(t[tx][ty + i]);
}

// ---------------------------------------------------------------------------
// bf16 MFMA GEMM, m97 structure: C[M,N] = A[M,K] @ Bt[N,K]^T
// ---------------------------------------------------------------------------
template <bool BF16_OUT, bool ADD_BIAS>
__global__ __launch_bounds__(256) void gemm_bt(const bf16* __restrict__ A,
                                               const bf16* __restrict__ Bt,
                                               void* __restrict__ Cout,
                                               const float* __restrict__ bp,
                                               int K, int N) {
  __shared__ bf16 As[128 * 32];
  __shared__ bf16 Bs[128 * 32];
  const int m0 = blockIdx.y * 128, n0 = blockIdx.x * 128;
  const int tid = threadIdx.x;
  const int lane = tid & 63, w = tid >> 6;
  const int wm = w >> 1, wn = w & 1;

  const int srow = lane >> 2, scol = (lane & 3) * 8;
  const int ca = w * 2;
  const bf16* Ag0 = A + (size_t)(m0 + ca * 16 + srow) * K + scol;
  const bf16* Ag1 = Ag0 + (size_t)16 * K;
  const bf16* Bg0 = Bt + (size_t)(n0 + ca * 16 + srow) * K + scol;
  const bf16* Bg1 = Bg0 + (size_t)16 * K;
  bf16* Al0 = As + ca * 512;
  bf16* Al1 = Al0 + 512;
  bf16* Bl0 = Bs + ca * 512;
  bf16* Bl1 = Bl0 + 512;

  f32x4 acc[4][4] = {};

  const int rr = lane & 15;
  const int kb = (lane >> 4) * 8;

  for (int k0 = 0; k0 < K; k0 += 32) {
    GLD16(Ag0 + k0, Al0);
    GLD16(Ag1 + k0, Al1);
    GLD16(Bg0 + k0, Bl0);
    GLD16(Bg1 + k0, Bl1);
    __syncthreads();
    short8v af[4], bfr[4];
#pragma unroll
    for (int i = 0; i < 4; ++i) {
      af[i]  = *(const short8v*)&As[(wm * 64 + i * 16 + rr) * 32 + kb];
      bfr[i] = *(const short8v*)&Bs[(wn * 64 + i * 16 + rr) * 32 + kb];
    }
#pragma unroll
    for (int i = 0; i < 4; ++i)
#pragma unroll
      for (int j = 0; j < 4; ++j)
        acc[i][j] = __builtin_amdgcn_mfma_f32_16x16x32_bf16(af[i], bfr[j], acc[i][j], 0, 0, 0);
    __syncthreads();
  }

  const int crow = (lane >> 4) * 4, ccol = lane & 15;
  if constexpr (BF16_OUT) {
    bf16* C = (bf16*)Cout;
#pragma unroll
    for (int i = 0; i < 4; ++i)
#pragma unroll
      for (int j = 0; j < 4; ++j) {
        const size_t base =
            (size_t)(m0 + wm * 64 + i * 16 + crow) * N + (n0 + wn * 64 + j * 16 + ccol);
#pragma unroll
        for (int jj = 0; jj < 4; ++jj)
          C[base + (size_t)jj * N] = __float2bfloat16(acc[i][j][jj]);
      }
  } else {
    float* C = (float*)Cout;
    float bv[4];
#pragma unroll
    for (int j = 0; j < 4; ++j)
      bv[j] = ADD_BIAS ? bp[n0 + wn * 64 + j * 16 + ccol] : 0.f;
#pragma unroll
    for (int i = 0; i < 4; ++i)
#pragma unroll
      for (int j = 0; j < 4; ++j) {
        const size_t base =
            (size_t)(m0 + wm * 64 + i * 16 + crow) * N + (n0 + wn * 64 + j * 16 + ccol);
#pragma unroll
        for (int jj = 0; jj < 4; ++jj)
          C[base + (size_t)jj * N] = acc[i][j][jj] + bv[j];
      }
  }
}

// ---------------------------------------------------------------------------
// LSTM recurrence via MFMA broadcast. One WG per (b,n) chain, 8 waves.
// Wave w owns d in [16w, 16w+16); lane holds all 4 gates for one d.
// R[g,n,:,:] resides in VGPRs as bf16 B-fragments. h broadcast via the
// matrix pipe (all A rows = h), double-buffered 512B LDS, 1 barrier/step.
// ---------------------------------------------------------------------------
__global__ __launch_bounds__(512) void lstm_mfma(const bf16* __restrict__ Wx,
                                                 const float* __restrict__ R,
                                                 const float* __restrict__ bias,
                                                 bf16* __restrict__ h_all) {
  const int wg = blockIdx.x;
  const int bb = wg >> 3;   // batch
  const int n = wg & 7;     // head
  const int tid = threadIdx.x;
  const int w = tid >> 6, lane = tid & 63;
  const int lg = lane >> 4;        // k-slice group 0..3
  const int lc = lane & 15;        // col within fragment
  const int d = w * 16 + lc;       // this lane's d

  // B fragments: lane holds R[g, n, d, 32*kf + 8*lg + j], j=0..7 (bf16)
  short8v Bf[4][4];
#pragma unroll
  for (int g = 0; g < 4; ++g)
#pragma unroll
    for (int kf = 0; kf < 4; ++kf) {
      const float* rp = R + (size_t)((g * Nq + n) * Dq + d) * Dq + 32 * kf + 8 * lg;
      const float4 r0 = *(const float4*)rp;
      const float4 r1 = *(const float4*)(rp + 4);
      short8v bv;
      bv[0] = (short)bfu(r0.x); bv[1] = (short)bfu(r0.y);
      bv[2] = (short)bfu(r0.z); bv[3] = (short)bfu(r0.w);
      bv[4] = (short)bfu(r1.x); bv[5] = (short)bfu(r1.y);
      bv[6] = (short)bfu(r1.z); bv[7] = (short)bfu(r1.w);
      Bf[g][kf] = bv;
    }

  float bvf[4];
#pragma unroll
  for (int g = 0; g < 4; ++g) bvf[g] = bias[(g * Nq + n) * Dq + d];

  __shared__ __align__(16) bf16 hbuf[2][128];
  if (tid < 128) hbuf[0][tid] = __float2bfloat16(0.f);
  __syncthreads();

  // Wx element (t,g) at wx0[t*4096 + g*1024]
  const bf16* wx0 = Wx + (size_t)bb * Tq * 4096 + n * Dq + d;
  bf16 wxA[4], wxB[4];
#pragma unroll
  for (int g = 0; g < 4; ++g) wxA[g] = wx0[g * 1024];
#pragma unroll
  for (int g = 0; g < 4; ++g) wxB[g] = wx0[4096 + g * 1024];

  float c = 0.f;

  for (int t = 0; t < Tq; ++t) {
    // A fragments: every lane reads h[32*kf + 8*lg .. +8] (broadcast groups)
    const bf16* hb = hbuf[t & 1];
    short8v Af[4];
#pragma unroll
    for (int kf = 0; kf < 4; ++kf)
      Af[kf] = *(const short8v*)(hb + 32 * kf + 8 * lg);

    // prefetch wx for t+2
    bf16 wxC[4];
    if (t < Tq - 2) {
#pragma unroll
      for (int g = 0; g < 4; ++g) wxC[g] = wx0[(size_t)(t + 2) * 4096 + g * 1024];
    } else {
#pragma unroll
      for (int g = 0; g < 4; ++g) wxC[g] = __float2bfloat16(0.f);
    }

    f32x4 acc[4];
#pragma unroll
    for (int g = 0; g < 4; ++g) {
      const float pre = __bfloat162float(wxA[g]) + bvf[g];
      acc[g][0] = pre; acc[g][1] = pre; acc[g][2] = pre; acc[g][3] = pre;
    }
#pragma unroll
    for (int g = 0; g < 4; ++g)
#pragma unroll
      for (int kf = 0; kf < 4; ++kf)
        acc[g] = __builtin_amdgcn_mfma_f32_16x16x32_bf16(Af[kf], Bf[g][kf], acc[g], 0, 0, 0);

    const float i_ = sigm(acc[0][0]);
    const float f_ = sigm(acc[1][0]);
    const float z_ = tanh_(acc[2][0]);
    const float o_ = sigm(acc[3][0]);
    c = f_ * c + i_ * z_;
    const float h = o_ * tanh_(c);

#pragma unroll
    for (int g = 0; g < 4; ++g) { wxA[g] = wxB[g]; wxB[g] = wxC[g]; }

    const bf16 h16 = __float2bfloat16(h);
    if (lane < 16) {
      hbuf[(t + 1) & 1][d] = h16;
      h_all[((size_t)(bb * Tq + t) * Nq + n) * Dq + d] = h16;
    }
    // barrier WITHOUT vmcnt drain: only LDS must be visible
    asm volatile("s_waitcnt lgkmcnt(0)" ::: "memory");
    __builtin_amdgcn_s_barrier();
  }
}

// ---------------------------------------------------------------------------
extern "C" void kernel_launch(void* const* d_in, const int* in_sizes, int n_in,
                              void* d_out, int out_size, void* d_ws, size_t ws_size,
                              hipStream_t stream) {
  const float* x_emb = (const float*)d_in[0];  // [16,1024,1024]
  const float* W_in  = (const float*)d_in[1];  // [1024,4096]
  const float* R     = (const float*)d_in[2];  // [4,8,128,128]
  const float* bias  = (const float*)d_in[3];  // [4,8,128]
  const float* W_prj = (const float*)d_in[4];  // [2048,1024]
  const float* b_prj = (const float*)d_in[5];  // [2048]

  char* ws = (char*)d_ws;
  bf16* xb  = (bf16*)ws;                               // 32 MB
  bf16* WiT = (bf16*)(ws + (size_t)M1 * K1 * 2);       //  8 MB
  bf16* Wpb = WiT + (size_t)N1q * K1;                  //  4 MB
  bf16* H   = Wpb + (size_t)N2 * K2;                   // 32 MB
  bf16* Wx = (bf16*)d_out;                             // 134 MB, dead before gemm_out

  cast_f32_bf16<<<(M1 * K1 / 4 + 255) / 256, 256, 0, stream>>>(x_emb, xb, M1 * K1 / 4);
  transpose_cast<<<dim3(N1q / 32, K1 / 32), 256, 0, stream>>>(W_in, WiT, K1, N1q);
  cast_f32_bf16<<<(N2 * K2 / 4 + 255) / 256, 256, 0, stream>>>(W_prj, Wpb, N2 * K2 / 4);

  gemm_bt<true, false><<<dim3(N1q / 128, M1 / 128), 256, 0, stream>>>(
      xb, WiT, (void*)Wx, nullptr, K1, N1q);

  lstm_mfma<<<dim3(Bq * Nq), 512, 0, stream>>>(Wx, R, bias, H);

  gemm_bt<false, true><<<dim3(N2 / 128, M1 / 128), 256, 0, stream>>>(
      H, Wpb, d_out, b_prj, K2, N2);
}

// Round 4
// 803.307 us; speedup vs baseline: 4.0644x; 1.3675x over previous
//
#include <hip/hip_runtime.h>
#include <hip/hip_bf16.h>

#define DEV __device__ __forceinline__

using bf16 = __hip_bfloat16;
typedef __attribute__((ext_vector_type(8))) short short8v;  // 8 bf16 = 4 VGPRs
typedef __attribute__((ext_vector_type(4))) float f32x4;

constexpr int Bq = 16, Tq = 1024, Eq = 1024, Gq = 4, Nq = 8, Dq = 128, Vq = 2048;
constexpr int M1 = Bq * Tq;        // 16384
constexpr int N1q = Gq * Nq * Dq;  // 4096
constexpr int K1 = Eq;             // 1024
constexpr int K2 = Nq * Dq;        // 1024
constexpr int N2 = Vq;             // 2048

DEV unsigned short bfu(float x) {
  union { bf16 h; unsigned short u; } cv;
  cv.h = __float2bfloat16(x);
  return cv.u;
}

DEV float rcp_(float x) { return __builtin_amdgcn_rcpf(x); }
DEV float sigm(float x) { return rcp_(1.0f + __expf(-x)); }
DEV float tanh_(float x) { return fmaf(2.0f, rcp_(1.0f + __expf(-2.0f * x)), -1.0f); }

// async global->LDS, 16B per lane; LDS dest is wave-uniform base + lane*16
#define GLD16(gp, lp)                                                       \
  __builtin_amdgcn_global_load_lds(                                        \
      (const __attribute__((address_space(1))) void*)(gp),                 \
      (__attribute__((address_space(3))) void*)(lp), 16, 0, 0)

// ---------------------------------------------------------------------------
// Prep kernels: casts + transpose-cast
// ---------------------------------------------------------------------------
__global__ __launch_bounds__(256) void cast_f32_bf16(const float* __restrict__ s,
                                                     bf16* __restrict__ d, int n4) {
  const int i = blockIdx.x * 256 + threadIdx.x;
  if (i >= n4) return;
  const float4 v = ((const float4*)s)[i];
  ushort4 u;
  u.x = bfu(v.x); u.y = bfu(v.y); u.z = bfu(v.z); u.w = bfu(v.w);
  ((ushort4*)d)[i] = u;
}

// s: [SK][SN] f32 row-major  ->  d: [SN][SK] bf16 row-major
__global__ __launch_bounds__(256) void transpose_cast(const float* __restrict__ s,
                                                      bf16* __restrict__ d,
                                                      int SK, int SN) {
  __shared__ float t[32][33];
  const int n0 = blockIdx.x * 32, k0 = blockIdx.y * 32;
  const int tx = threadIdx.x & 31, ty = threadIdx.x >> 5;  // ty: 0..7
#pragma unroll
  for (int i = 0; i < 32; i += 8)
    t[ty + i][tx] = s[(size_t)(k0 + ty + i) * SN + n0 + tx];
  __syncthreads();
#pragma unroll
  for (int i = 0; i < 32; i += 8)
    d[(size_t)(n0 + ty + i) * SK + k0 + tx] = __float2bfloat16(t[tx][ty + i]);
}

// ---------------------------------------------------------------------------
// bf16 MFMA GEMM, m97 structure: C[M,N] = A[M,K] @ Bt[N,K]^T
// ---------------------------------------------------------------------------
template <bool BF16_OUT, bool ADD_BIAS>
__global__ __launch_bounds__(256) void gemm_bt(const bf16* __restrict__ A,
                                               const bf16* __restrict__ Bt,
                                               void* __restrict__ Cout,
                                               const float* __restrict__ bp,
                                               int K, int N) {
  __shared__ bf16 As[128 * 32];
  __shared__ bf16 Bs[128 * 32];
  const int m0 = blockIdx.y * 128, n0 = blockIdx.x * 128;
  const int tid = threadIdx.x;
  const int lane = tid & 63, w = tid >> 6;
  const int wm = w >> 1, wn = w & 1;

  const int srow = lane >> 2, scol = (lane & 3) * 8;
  const int ca = w * 2;
  const bf16* Ag0 = A + (size_t)(m0 + ca * 16 + srow) * K + scol;
  const bf16* Ag1 = Ag0 + (size_t)16 * K;
  const bf16* Bg0 = Bt + (size_t)(n0 + ca * 16 + srow) * K + scol;
  const bf16* Bg1 = Bg0 + (size_t)16 * K;
  bf16* Al0 = As + ca * 512;
  bf16* Al1 = Al0 + 512;
  bf16* Bl0 = Bs + ca * 512;
  bf16* Bl1 = Bl0 + 512;

  f32x4 acc[4][4] = {};

  const int rr = lane & 15;
  const int kb = (lane >> 4) * 8;

  for (int k0 = 0; k0 < K; k0 += 32) {
    GLD16(Ag0 + k0, Al0);
    GLD16(Ag1 + k0, Al1);
    GLD16(Bg0 + k0, Bl0);
    GLD16(Bg1 + k0, Bl1);
    __syncthreads();
    short8v af[4], bfr[4];
#pragma unroll
    for (int i = 0; i < 4; ++i) {
      af[i]  = *(const short8v*)&As[(wm * 64 + i * 16 + rr) * 32 + kb];
      bfr[i] = *(const short8v*)&Bs[(wn * 64 + i * 16 + rr) * 32 + kb];
    }
#pragma unroll
    for (int i = 0; i < 4; ++i)
#pragma unroll
      for (int j = 0; j < 4; ++j)
        acc[i][j] = __builtin_amdgcn_mfma_f32_16x16x32_bf16(af[i], bfr[j], acc[i][j], 0, 0, 0);
    __syncthreads();
  }

  const int crow = (lane >> 4) * 4, ccol = lane & 15;
  if constexpr (BF16_OUT) {
    bf16* C = (bf16*)Cout;
#pragma unroll
    for (int i = 0; i < 4; ++i)
#pragma unroll
      for (int j = 0; j < 4; ++j) {
        const size_t base =
            (size_t)(m0 + wm * 64 + i * 16 + crow) * N + (n0 + wn * 64 + j * 16 + ccol);
#pragma unroll
        for (int jj = 0; jj < 4; ++jj)
          C[base + (size_t)jj * N] = __float2bfloat16(acc[i][j][jj]);
      }
  } else {
    float* C = (float*)Cout;
    float bv[4];
#pragma unroll
    for (int j = 0; j < 4; ++j)
      bv[j] = ADD_BIAS ? bp[n0 + wn * 64 + j * 16 + ccol] : 0.f;
#pragma unroll
    for (int i = 0; i < 4; ++i)
#pragma unroll
      for (int j = 0; j < 4; ++j) {
        const size_t base =
            (size_t)(m0 + wm * 64 + i * 16 + crow) * N + (n0 + wn * 64 + j * 16 + ccol);
#pragma unroll
        for (int jj = 0; jj < 4; ++jj)
          C[base + (size_t)jj * N] = acc[i][j][jj] + bv[j];
      }
  }
}

// ---------------------------------------------------------------------------
// LSTM recurrence via MFMA broadcast. One WG per (b,n) chain, 8 waves.
// v4 changes vs round 3:
//  - Wx prefetch: 4-deep STATIC register pipeline (loop unrolled x4, no
//    register rotation -> compiler emits deep counted vmcnt, HBM latency
//    fully hidden across 4 steps).
//  - MFMA accumulation depth 4 -> 2 (two parallel accumulator chains).
//  - branch-free activations on all lanes; only stores predicated.
//  - sched_barrier fences around the lgkm-only barrier (rule #18).
// ---------------------------------------------------------------------------
__global__ __launch_bounds__(512) void lstm_mfma(const bf16* __restrict__ Wx,
                                                 const float* __restrict__ R,
                                                 const float* __restrict__ bias,
                                                 bf16* __restrict__ h_all) {
  const int wg = blockIdx.x;
  const int bb = wg >> 3;   // batch
  const int n = wg & 7;     // head
  const int tid = threadIdx.x;
  const int w = tid >> 6, lane = tid & 63;
  const int lg = lane >> 4;        // k-slice group 0..3
  const int lc = lane & 15;        // col within fragment
  const int d = w * 16 + lc;       // this lane's d

  // B fragments: lane holds R[g, n, d, 32*kf + 8*lg + j], j=0..7 (bf16)
  short8v Bf[4][4];
#pragma unroll
  for (int g = 0; g < 4; ++g)
#pragma unroll
    for (int kf = 0; kf < 4; ++kf) {
      const float* rp = R + (size_t)((g * Nq + n) * Dq + d) * Dq + 32 * kf + 8 * lg;
      const float4 r0 = *(const float4*)rp;
      const float4 r1 = *(const float4*)(rp + 4);
      short8v bv;
      bv[0] = (short)bfu(r0.x); bv[1] = (short)bfu(r0.y);
      bv[2] = (short)bfu(r0.z); bv[3] = (short)bfu(r0.w);
      bv[4] = (short)bfu(r1.x); bv[5] = (short)bfu(r1.y);
      bv[6] = (short)bfu(r1.z); bv[7] = (short)bfu(r1.w);
      Bf[g][kf] = bv;
    }

  float bvf[4];
#pragma unroll
  for (int g = 0; g < 4; ++g) bvf[g] = bias[(g * Nq + n) * Dq + d];

  __shared__ __align__(16) bf16 hbuf[2][128];
  if (tid < 128) hbuf[0][tid] = __float2bfloat16(0.f);
  __syncthreads();

  // Wx element (t,g) at wx0[t*4096 + g*1024]
  const bf16* wx0 = Wx + (size_t)bb * Tq * 4096 + n * Dq + d;
  bf16* hallp = h_all + ((size_t)(bb * Tq) * Nq + n) * Dq + d;

  // 4-deep static prefetch pipeline (no rotation!)
  bf16 wxr[4][4];
#pragma unroll
  for (int u = 0; u < 4; ++u)
#pragma unroll
    for (int g = 0; g < 4; ++g) wxr[u][g] = wx0[(size_t)u * 4096 + g * 1024];

  float c = 0.f;

  for (int t0 = 0; t0 < Tq; t0 += 4) {
#pragma unroll
    for (int u = 0; u < 4; ++u) {
      const int t = t0 + u;
      // A fragments: every lane reads h[32*kf + 8*lg .. +8] (broadcast groups)
      const bf16* hb = hbuf[t & 1];
      short8v Af[4];
#pragma unroll
      for (int kf = 0; kf < 4; ++kf)
        Af[kf] = *(const short8v*)(hb + 32 * kf + 8 * lg);

      // two parallel accumulator chains per gate (depth 2)
      f32x4 accA[4], accB[4];
#pragma unroll
      for (int g = 0; g < 4; ++g) {
        const float pre = __bfloat162float(wxr[u][g]) + bvf[g];
        accA[g][0] = pre; accA[g][1] = pre; accA[g][2] = pre; accA[g][3] = pre;
        accB[g][0] = 0.f; accB[g][1] = 0.f; accB[g][2] = 0.f; accB[g][3] = 0.f;
      }
#pragma unroll
      for (int g = 0; g < 4; ++g) {
        accA[g] = __builtin_amdgcn_mfma_f32_16x16x32_bf16(Af[0], Bf[g][0], accA[g], 0, 0, 0);
        accB[g] = __builtin_amdgcn_mfma_f32_16x16x32_bf16(Af[2], Bf[g][2], accB[g], 0, 0, 0);
        accA[g] = __builtin_amdgcn_mfma_f32_16x16x32_bf16(Af[1], Bf[g][1], accA[g], 0, 0, 0);
        accB[g] = __builtin_amdgcn_mfma_f32_16x16x32_bf16(Af[3], Bf[g][3], accB[g], 0, 0, 0);
      }

      // prefetch wx for step t+4 into the SAME static slot (used 4 steps later)
      {
        const int tp = (t + 4 < Tq) ? (t + 4) : (Tq - 1);
#pragma unroll
        for (int g = 0; g < 4; ++g) wxr[u][g] = wx0[(size_t)tp * 4096 + g * 1024];
      }

      const float i_ = sigm(accA[0][0] + accB[0][0]);
      const float f_ = sigm(accA[1][0] + accB[1][0]);
      const float z_ = tanh_(accA[2][0] + accB[2][0]);
      const float o_ = sigm(accA[3][0] + accB[3][0]);
      c = f_ * c + i_ * z_;
      const float h = o_ * tanh_(c);
      const bf16 h16 = __float2bfloat16(h);

      if (lg == 0) {
        hbuf[(t + 1) & 1][d] = h16;
        hallp[(size_t)t * (Nq * Dq)] = h16;
      }
      // barrier WITHOUT vmcnt drain: only LDS visibility needed.
      __builtin_amdgcn_sched_barrier(0);
      asm volatile("s_waitcnt lgkmcnt(0)" ::: "memory");
      __builtin_amdgcn_sched_barrier(0);
      __builtin_amdgcn_s_barrier();
      __builtin_amdgcn_sched_barrier(0);
    }
  }
}

// ---------------------------------------------------------------------------
extern "C" void kernel_launch(void* const* d_in, const int* in_sizes, int n_in,
                              void* d_out, int out_size, void* d_ws, size_t ws_size,
                              hipStream_t stream) {
  const float* x_emb = (const float*)d_in[0];  // [16,1024,1024]
  const float* W_in  = (const float*)d_in[1];  // [1024,4096]
  const float* R     = (const float*)d_in[2];  // [4,8,128,128]
  const float* bias  = (const float*)d_in[3];  // [4,8,128]
  const float* W_prj = (const float*)d_in[4];  // [2048,1024]
  const float* b_prj = (const float*)d_in[5];  // [2048]

  char* ws = (char*)d_ws;
  bf16* xb  = (bf16*)ws;                               // 32 MB
  bf16* WiT = (bf16*)(ws + (size_t)M1 * K1 * 2);       //  8 MB
  bf16* Wpb = WiT + (size_t)N1q * K1;                  //  4 MB
  bf16* H   = Wpb + (size_t)N2 * K2;                   // 32 MB
  bf16* Wx = (bf16*)d_out;                             // 134 MB, dead before gemm_out

  cast_f32_bf16<<<(M1 * K1 / 4 + 255) / 256, 256, 0, stream>>>(x_emb, xb, M1 * K1 / 4);
  transpose_cast<<<dim3(N1q / 32, K1 / 32), 256, 0, stream>>>(W_in, WiT, K1, N1q);
  cast_f32_bf16<<<(N2 * K2 / 4 + 255) / 256, 256, 0, stream>>>(W_prj, Wpb, N2 * K2 / 4);

  gemm_bt<true, false><<<dim3(N1q / 128, M1 / 128), 256, 0, stream>>>(
      xb, WiT, (void*)Wx, nullptr, K1, N1q);

  lstm_mfma<<<dim3(Bq * Nq), 512, 0, stream>>>(Wx, R, bias, H);

  gemm_bt<false, true><<<dim3(N2 / 128, M1 / 128), 256, 0, stream>>>(
      H, Wpb, d_out, b_prj, K2, N2);
}